// Round 1
// baseline (1261.323 us; speedup 1.0000x reference)
//
#include <hip/hip_runtime.h>

#define DIN 64
#define NREL 8

// One wave (64 lanes) per edge; lane i handles feature dim i.
__global__ __launch_bounds__(256) void rgcn_edge_kernel(
    const float* __restrict__ x,     // (N, 64)
    const int* __restrict__ src,
    const int* __restrict__ dst,
    const int* __restrict__ et,
    float* __restrict__ acc,         // (G, N, 64)
    float* __restrict__ cnt,         // (G, N)
    int n_edges, int n_nodes, int g0, int G)
{
    const int lane = threadIdx.x & 63;
    const int e = blockIdx.x * 4 + (threadIdx.x >> 6);
    if (e >= n_edges) return;
    const int r = et[e] - g0;
    if ((unsigned)r >= (unsigned)G) return;
    const int s = src[e];
    const int d = dst[e];
    const float v = x[(size_t)s * DIN + lane];
    atomicAdd(&acc[((size_t)r * n_nodes + d) * DIN + lane], v);
    if (lane == 0) atomicAdd(&cnt[(size_t)r * n_nodes + d], 1.0f);
}

// Fused node transform: out = [x | mean_r...] @ [root; W_r...] + b (+relu)
// Block = 256 threads; thread computes a 4(node) x 4(j) register tile.
template <int DOUT>
__global__ __launch_bounds__(256) void rgcn_node_kernel(
    const float* __restrict__ xin,   // (N, 64)
    const float* __restrict__ acc,   // (G, N, 64)
    const float* __restrict__ cnt,   // (G, N)
    const float* __restrict__ W,     // (8, 64, DOUT)
    const float* __restrict__ root,  // (64, DOUT)
    const float* __restrict__ bias,  // (DOUT)
    float* __restrict__ out,         // (N, DOUT)
    int n_nodes, int g0, int G, int do_relu)
{
    constexpr int JT = DOUT / 4;        // threads along j (each covers 4 j)
    constexpr int MT = 256 / JT;        // threads along m (each covers 4 nodes)
    constexpr int NODES = MT * 4;       // nodes per block
    constexpr int AS = 68;              // padded row stride (floats), 16B-aligned, breaks conflicts
    __shared__ float as[NODES * AS];
    __shared__ float ws[DIN * DOUT];

    const int t = threadIdx.x;
    const int jt = t % JT;
    const int mt = t / JT;
    const int node0 = blockIdx.x * NODES;

    float4 sum[4];
#pragma unroll
    for (int m = 0; m < 4; ++m) sum[m] = float4{0.f, 0.f, 0.f, 0.f};

    // cooperative loaders
    auto load_rows = [&](const float* rowsrc) {
#pragma unroll
        for (int i = t; i < NODES * DIN; i += 256) {
            const int row = i >> 6;
            const int col = i & 63;
            const int node = node0 + row;
            as[row * AS + col] =
                (node < n_nodes) ? rowsrc[(size_t)node * DIN + col] : 0.0f;
        }
    };
    auto load_w = [&](const float* wsrc) {
        const float4* s4 = (const float4*)wsrc;
        float4* d4 = (float4*)ws;
#pragma unroll
        for (int i = t; i < (DIN * DOUT) / 4; i += 256) d4[i] = s4[i];
    };

    float4 racc[4];
    auto compute = [&]() {
#pragma unroll
        for (int m = 0; m < 4; ++m) racc[m] = float4{0.f, 0.f, 0.f, 0.f};
#pragma unroll 4
        for (int k = 0; k < DIN; k += 4) {
            const float4 w0 = *(const float4*)&ws[(k + 0) * DOUT + jt * 4];
            const float4 w1 = *(const float4*)&ws[(k + 1) * DOUT + jt * 4];
            const float4 w2 = *(const float4*)&ws[(k + 2) * DOUT + jt * 4];
            const float4 w3 = *(const float4*)&ws[(k + 3) * DOUT + jt * 4];
#pragma unroll
            for (int m = 0; m < 4; ++m) {
                const float4 av = *(const float4*)&as[(mt * 4 + m) * AS + k];
                racc[m].x += av.x * w0.x + av.y * w1.x + av.z * w2.x + av.w * w3.x;
                racc[m].y += av.x * w0.y + av.y * w1.y + av.z * w2.y + av.w * w3.y;
                racc[m].z += av.x * w0.z + av.y * w1.z + av.z * w2.z + av.w * w3.z;
                racc[m].w += av.x * w0.w + av.y * w1.w + av.z * w2.w + av.w * w3.w;
            }
        }
    };

    // self-loop (root) segment, only in the first relation-group pass
    if (g0 == 0) {
        load_rows(xin);
        load_w(root);
        __syncthreads();
        compute();
#pragma unroll
        for (int m = 0; m < 4; ++m) {
            sum[m].x += racc[m].x; sum[m].y += racc[m].y;
            sum[m].z += racc[m].z; sum[m].w += racc[m].w;
        }
        __syncthreads();
    }

    for (int r = 0; r < G; ++r) {
        load_rows(acc + (size_t)r * n_nodes * DIN);
        load_w(W + (size_t)(g0 + r) * DIN * DOUT);
        __syncthreads();
        compute();
#pragma unroll
        for (int m = 0; m < 4; ++m) {
            const int node = node0 + mt * 4 + m;
            float c = (node < n_nodes) ? cnt[(size_t)r * n_nodes + node] : 0.0f;
            const float sc = (c > 0.0f) ? (1.0f / c) : 0.0f;
            sum[m].x += racc[m].x * sc; sum[m].y += racc[m].y * sc;
            sum[m].z += racc[m].z * sc; sum[m].w += racc[m].w * sc;
        }
        __syncthreads();
    }

    // epilogue
    float4 bv = float4{0.f, 0.f, 0.f, 0.f};
    if (g0 == 0) bv = *(const float4*)&bias[jt * 4];
#pragma unroll
    for (int m = 0; m < 4; ++m) {
        const int node = node0 + mt * 4 + m;
        if (node >= n_nodes) continue;
        float4 v = sum[m];
        if (g0 == 0) {
            v.x += bv.x; v.y += bv.y; v.z += bv.z; v.w += bv.w;
        } else {
            const float4 o = *(const float4*)&out[(size_t)node * DOUT + jt * 4];
            v.x += o.x; v.y += o.y; v.z += o.z; v.w += o.w;
        }
        if (do_relu) {
            v.x = fmaxf(v.x, 0.f); v.y = fmaxf(v.y, 0.f);
            v.z = fmaxf(v.z, 0.f); v.w = fmaxf(v.w, 0.f);
        }
        *(float4*)&out[(size_t)node * DOUT + jt * 4] = v;
    }
}

extern "C" void kernel_launch(void* const* d_in, const int* in_sizes, int n_in,
                              void* d_out, int out_size, void* d_ws, size_t ws_size,
                              hipStream_t stream) {
    const float* x     = (const float*)d_in[0];
    const float* W1    = (const float*)d_in[1];
    const float* root1 = (const float*)d_in[2];
    const float* b1    = (const float*)d_in[3];
    const float* W2    = (const float*)d_in[4];
    const float* root2 = (const float*)d_in[5];
    const float* b2    = (const float*)d_in[6];
    const int*   src   = (const int*)d_in[7];
    const int*   dst   = (const int*)d_in[8];
    const int*   et    = (const int*)d_in[9];

    const int N = in_sizes[0] / DIN;
    const int E = in_sizes[7];

    // workspace layout: h (N*64) | cnt (8*N) | acc (G*N*64)
    float* h   = (float*)d_ws;
    float* cnt = h + (size_t)N * DIN;
    float* acc = cnt + (size_t)NREL * N;

    // relation-group size that fits the workspace
    size_t avail_floats = ws_size / sizeof(float);
    long rem = (long)avail_floats - (long)N * DIN - (long)NREL * N;
    int G = (int)(rem / ((long)N * DIN));
    if (G > NREL) G = NREL;
    if (G < 1) G = 1;

    const int edge_blocks = (E + 3) / 4;

    auto run_layer = [&](const float* xin, const float* W, const float* root,
                         const float* b, float* out, int dout, bool relu) {
        for (int g0 = 0; g0 < NREL; g0 += G) {
            const int g = (g0 + G <= NREL) ? G : (NREL - g0);
            hipMemsetAsync(cnt, 0, (size_t)g * N * sizeof(float), stream);
            hipMemsetAsync(acc, 0, (size_t)g * N * DIN * sizeof(float), stream);
            rgcn_edge_kernel<<<edge_blocks, 256, 0, stream>>>(
                xin, src, dst, et, acc, cnt, E, N, g0, g);
            const bool last = (g0 + g >= NREL);
            const int do_relu = (relu && last) ? 1 : 0;
            if (dout == 64) {
                const int nb = (N + 63) / 64;
                rgcn_node_kernel<64><<<nb, 256, 0, stream>>>(
                    xin, acc, cnt, W, root, b, out, N, g0, g, do_relu);
            } else {
                const int nb = (N + 127) / 128;
                rgcn_node_kernel<32><<<nb, 256, 0, stream>>>(
                    xin, acc, cnt, W, root, b, out, N, g0, g, do_relu);
            }
        }
    };

    run_layer(x, W1, root1, b1, h, 64, true);
    run_layer(h, W2, root2, b2, (float*)d_out, 32, false);
}